// Round 1
// 355.332 us; speedup vs baseline: 1.0459x; 1.0459x over previous
//
#include <hip/hip_runtime.h>
#include <math.h>

#define Bq 32
#define Sq 2048
#define Dq 1024
#define Tq 8
#define TILE 64            // S-rows per block in kernel A
#define NT (Sq / TILE)     // 32 tiles per batch row

typedef float f32x4 __attribute__((ext_vector_type(4)));

// ---------------------------------------------------------------------------
// Kernel A: for each 64-row tile of (b):
//   scores[b,s] = dot(qry[b,:], ctx[b,s,:]) + log(mask[b,s])   (written out)
//   partial[b,tile,:] = sum_{s in tile} exp(scores[s] - m_tile) * ctx[b,s,:]
// 8 waves/block, each owns 8 rows as two 4-row register-resident chunks with
// online max-rescale; cross-wave combine rescales by exp(m_wave - m_tile).
// ctx is read from HBM exactly once (nontemporal: streamed, read-once).
// Grid (NT, B) = (32, 32), block 512.
// ---------------------------------------------------------------------------
__global__ __launch_bounds__(512) void fused_scores_partial_kernel(
    const float* __restrict__ qry, const float* __restrict__ ctx,
    const float* __restrict__ mask, float* __restrict__ scores,
    f32x4* __restrict__ partial)
{
    const int b    = blockIdx.y;
    const int tile = blockIdx.x;
    const int s0   = tile * TILE;
    const int wave = threadIdx.x >> 6;   // 0..7
    const int lane = threadIdx.x & 63;

    __shared__ float wmax[8];
    __shared__ f32x4 buf[8 * 256];       // 32 KB wave-partial exchange

    const f32x4* q4 = (const f32x4*)(qry + (size_t)b * Dq);
    f32x4 q[4];
#pragma unroll
    for (int k = 0; k < 4; ++k) q[k] = q4[lane + 64 * k];

    f32x4 pacc[4];
#pragma unroll
    for (int k = 0; k < 4; ++k) pacc[k] = (f32x4){0.f, 0.f, 0.f, 0.f};
    float mw = -INFINITY;

#pragma unroll
    for (int p = 0; p < 2; ++p) {
        const int sbase = s0 + wave * 8 + p * 4;

        f32x4 c[4][4];
#pragma unroll
        for (int r = 0; r < 4; ++r) {
            const f32x4* c4 = (const f32x4*)(ctx + ((size_t)b * Sq + sbase + r) * Dq);
#pragma unroll
            for (int k = 0; k < 4; ++k)
                c[r][k] = __builtin_nontemporal_load(c4 + lane + 64 * k);
        }

        float sc[4];
#pragma unroll
        for (int r = 0; r < 4; ++r) {
            f32x4 prod = q[0] * c[r][0] + q[1] * c[r][1]
                       + q[2] * c[r][2] + q[3] * c[r][3];
            float acc = (prod.x + prod.y) + (prod.z + prod.w);
#pragma unroll
            for (int off = 1; off < 64; off <<= 1)   // butterfly: all lanes get sum
                acc += __shfl_xor(acc, off, 64);
            const float mk = mask[(size_t)b * Sq + sbase + r];
            acc += (mk == 1.0f) ? 0.0f : logf(mk);   // log(1)=0 exactly; skip transcendental
            sc[r] = acc;
            if (lane == 0) scores[(size_t)b * Sq + sbase + r] = acc;
        }

        const float mc = fmaxf(fmaxf(sc[0], sc[1]), fmaxf(sc[2], sc[3]));
        const float mnew = fmaxf(mw, mc);
        const float scale = (p == 0) ? 0.f : expf(mw - mnew); // p==0: pacc is 0
        mw = mnew;
#pragma unroll
        for (int k = 0; k < 4; ++k) pacc[k] = pacc[k] * scale;
#pragma unroll
        for (int r = 0; r < 4; ++r) {
            const float e = expf(sc[r] - mw);
#pragma unroll
            for (int k = 0; k < 4; ++k) pacc[k] += e * c[r][k];
        }
    }

    if (lane == 0) wmax[wave] = mw;
#pragma unroll
    for (int k = 0; k < 4; ++k) buf[wave * 256 + lane + 64 * k] = pacc[k];
    __syncthreads();

    const int t = threadIdx.x;
    if (t < 256) {
        float mt = wmax[0];
#pragma unroll
        for (int w = 1; w < 8; ++w) mt = fmaxf(mt, wmax[w]);
        f32x4 sum = (f32x4){0.f, 0.f, 0.f, 0.f};
#pragma unroll
        for (int w = 0; w < 8; ++w) {
            const float f = expf(wmax[w] - mt);
            sum += f * buf[w * 256 + t];
        }
        partial[((size_t)b * NT + tile) * 256 + t] = sum;
    }
}

// ---------------------------------------------------------------------------
// Kernel B: one 512-thread block per batch row.
//   1. softmax over scores (recomputed from A's bit-exact output)
//   2. alphas = min(parent, softmax); compact clipped rows (alpha > parent)
//   3. summary = sum_tile exp(m_tile - m)/Z * partial[tile]  -  sparse corr.
//      (tile loop split across two thread-halves, combined via LDS)
// E[#clipped rows] per b is ~1; exact for any data (capacity Sq).
// ---------------------------------------------------------------------------
__global__ __launch_bounds__(512) void finalize_kernel(
    const float* __restrict__ ctx, const float* __restrict__ scores,
    const float* __restrict__ prevatts, const int* __restrict__ parent_ptr,
    const f32x4* __restrict__ partial, float* __restrict__ alphas,
    f32x4* __restrict__ summary)
{
    const int b    = blockIdx.x;
    const int t    = threadIdx.x;
    const int wave = t >> 6;
    const int lane = t & 63;

    __shared__ float ssc[Sq];       // 8 KB: staged scores row
    __shared__ float redA[8], redB[8];
    __shared__ float ftile[NT];     // per-tile rescale factor
    __shared__ int   sidx[Sq];      // clipped-row indices (worst case all)
    __shared__ float sg[Sq];        // clipped-row excess alpha-p
    __shared__ f32x4 sum2[256];     // 4 KB: second-half tile sums
    __shared__ int   scount;

    if (t == 0) scount = 0;

    const float* srow = scores + (size_t)b * Sq;
    float vals[4];
    float m = -INFINITY;
#pragma unroll
    for (int i = 0; i < 4; ++i) {
        float v = srow[t + 512 * i];
        ssc[t + 512 * i] = v;
        vals[i] = v;
        m = fmaxf(m, v);
    }
#pragma unroll
    for (int off = 1; off < 64; off <<= 1)
        m = fmaxf(m, __shfl_xor(m, off, 64));
    if (lane == 0) redA[wave] = m;
    __syncthreads();                       // also covers ssc writes + scount init
    m = redA[0];
#pragma unroll
    for (int w = 1; w < 8; ++w) m = fmaxf(m, redA[w]);

    float sum = 0.f;
#pragma unroll
    for (int i = 0; i < 4; ++i) {
        vals[i] = expf(vals[i] - m);
        sum += vals[i];
    }
#pragma unroll
    for (int off = 1; off < 64; off <<= 1)
        sum += __shfl_xor(sum, off, 64);
    if (lane == 0) redB[wave] = sum;
    __syncthreads();
    sum = 0.f;
#pragma unroll
    for (int w = 0; w < 8; ++w) sum += redB[w];
    const float invZ = 1.0f / sum;

    // per-tile rescale factor: exp(m_tile - m) / Z  (m_tile from bit-exact ssc;
    // fmax over the same 64 floats A maxed -> bit-identical to A's tile max)
    if (t < NT) {
        float tm = -INFINITY;
#pragma unroll
        for (int i = 0; i < TILE; ++i) tm = fmaxf(tm, ssc[t * TILE + i]);
        ftile[t] = expf(tm - m) * invZ;
    }

    // alphas + compaction of clipped rows
    const float* par = prevatts + ((size_t)b * Tq + parent_ptr[b]) * Sq;
#pragma unroll
    for (int i = 0; i < 4; ++i) {
        const int s = t + 512 * i;
        const float a = vals[i] * invZ;
        const float p = par[s];
        alphas[(size_t)b * Sq + s] = fminf(p, a);
        const float g = a - p;
        if (g > 0.f) {
            int pos = atomicAdd(&scount, 1);
            sidx[pos] = s;
            sg[pos]  = g;
        }
    }
    __syncthreads();                       // covers ftile, sidx/sg, scount

    // summary = sum_tile ftile * partial[tile] - sum_clipped g * ctx_row
    // half 0: tiles 0..15, half 1: tiles 16..31, combine via LDS
    const f32x4* pp = partial + (size_t)b * NT * 256;
    const int half = t >> 8;
    const int tt   = t & 255;
    f32x4 acc = (f32x4){0.f, 0.f, 0.f, 0.f};
#pragma unroll
    for (int j = 0; j < 16; ++j) {
        const int tl = half * 16 + j;
        acc += ftile[tl] * pp[(size_t)tl * 256 + tt];
    }
    if (half) sum2[tt] = acc;
    __syncthreads();
    if (!half) {
        acc += sum2[tt];
        const int cnt = scount;
        const f32x4* cb = (const f32x4*)(ctx + (size_t)b * Sq * Dq);
        for (int i = 0; i < cnt; ++i) {
            acc -= sg[i] * cb[(size_t)sidx[i] * 256 + tt];
        }
        summary[b * 256 + tt] = acc;
    }
}

extern "C" void kernel_launch(void* const* d_in, const int* in_sizes, int n_in,
                              void* d_out, int out_size, void* d_ws, size_t ws_size,
                              hipStream_t stream)
{
    const float* qry        = (const float*)d_in[0];
    const float* ctx        = (const float*)d_in[1];
    const float* mask       = (const float*)d_in[2];
    const float* prevatts   = (const float*)d_in[3];
    const int*   parent_ptr = (const int*)d_in[4];

    float* out     = (float*)d_out;
    float* alphas  = out;                      // B*S = 65536
    float* summary = out + Bq * Sq;            // B*D = 32768
    float* scores  = out + Bq * Sq + Bq * Dq;  // B*S = 65536

    f32x4* partial = (f32x4*)d_ws;             // B*NT*D floats = 4 MB

    fused_scores_partial_kernel<<<dim3(NT, Bq), 512, 0, stream>>>(
        qry, ctx, mask, scores, partial);
    finalize_kernel<<<Bq, 512, 0, stream>>>(
        ctx, scores, prevatts, parent_ptr, partial, alphas, (f32x4*)summary);
}